// Round 1
// baseline (161.922 us; speedup 1.0000x reference)
//
#include <hip/hip_runtime.h>
#include <math.h>

#define MAX_OBJ 64
#define PF_ITEMS 8
#define TOPK_CHUNKS 32

// ---------------------------------------------------------------------------
// ws layout (host computes offsets):
//   double sums[3]            : conf_pos_sum, loc_sum, hardneg_sum
//   int2   state[B]           : {prefix_bits, remK} for radix select
//   int    n_pos[B]
//   u64    prior_fo[B*n_obj]  : packed (iou_bits<<32)|(~p) argmax per object
//   u32    hist[B*256]
//   float  conf_neg[B*P]
//   u64    best_pair[B*P]     : packed (iou_bits<<32)|obj per prior
// ---------------------------------------------------------------------------

__global__ void mbl_init_ws(double* __restrict__ sums, int* __restrict__ n_pos,
                            unsigned long long* __restrict__ prior_fo, int B, int n_obj) {
  int i = blockIdx.x * blockDim.x + threadIdx.x;
  if (i < 3) sums[i] = 0.0;
  if (i < B) n_pos[i] = 0;
  if (i < B * n_obj) prior_fo[i] = 0ULL;
}

// Phase A: per-prior best object + per-object best prior.
template <int NOBJ>
__global__ __launch_bounds__(256) void mbl_match_kernel(
    const float* __restrict__ boxes,             // [B, n_obj, 6] xyz
    const float* __restrict__ priors,            // [P, 6] cxcycz
    unsigned long long* __restrict__ prior_fo,   // [B, n_obj]
    unsigned long long* __restrict__ best_pair,  // [B, P]
    int P, int n_obj) {
  const int b = blockIdx.y;
  const int tid = threadIdx.x;
  __shared__ float s_box[NOBJ][6];
  __shared__ float s_vol[NOBJ];
  __shared__ unsigned long long s_part[4][NOBJ];
  for (int i = tid; i < n_obj * 6; i += blockDim.x)
    s_box[i / 6][i % 6] = boxes[(size_t)b * n_obj * 6 + i];
  __syncthreads();
  if (tid < n_obj) {
    s_vol[tid] = ((s_box[tid][3] - s_box[tid][0]) * (s_box[tid][4] - s_box[tid][1])) *
                 (s_box[tid][5] - s_box[tid][2]);
  }
  __syncthreads();

  unsigned long long pk[NOBJ];
#pragma unroll
  for (int o = 0; o < NOBJ; ++o) pk[o] = 0ULL;

  const int base = blockIdx.x * (blockDim.x * PF_ITEMS);
  for (int k = 0; k < PF_ITEMS; ++k) {
    const int p = base + k * blockDim.x + tid;
    if (p < P) {
      const float* pr = priors + (size_t)p * 6;
      const float pc0 = pr[0], pc1 = pr[1], pc2 = pr[2];
      const float ps0 = pr[3], ps1 = pr[4], ps2 = pr[5];
      const float plo0 = pc0 - ps0 * 0.5f, plo1 = pc1 - ps1 * 0.5f, plo2 = pc2 - ps2 * 0.5f;
      const float phi0 = pc0 + ps0 * 0.5f, phi1 = pc1 + ps1 * 0.5f, phi2 = pc2 + ps2 * 0.5f;
      const float vb = ((phi0 - plo0) * (phi1 - plo1)) * (phi2 - plo2);
      const unsigned invp = 0xFFFFFFFFu - (unsigned)p;
      float best = 0.f;
      int bobj = 0;
#pragma unroll
      for (int o = 0; o < NOBJ; ++o) {
        if (o >= n_obj) break;
        const float d0 = fminf(s_box[o][3], phi0) - fmaxf(s_box[o][0], plo0);
        const float d1 = fminf(s_box[o][4], phi1) - fmaxf(s_box[o][1], plo1);
        const float d2 = fminf(s_box[o][5], phi2) - fmaxf(s_box[o][2], plo2);
        const float inter = (fmaxf(d0, 0.f) * fmaxf(d1, 0.f)) * fmaxf(d2, 0.f);
        const float iou = inter / ((s_vol[o] + vb) - inter);
        const unsigned long long pkv =
            ((unsigned long long)__float_as_uint(iou) << 32) | invp;
        if (pkv > pk[o]) pk[o] = pkv;
        if (o == 0 || iou > best) { best = iou; bobj = o; }  // first-occurrence argmax
      }
      best_pair[(size_t)b * P + p] =
          ((unsigned long long)__float_as_uint(best) << 32) | (unsigned)bobj;
    }
  }

  const int lane = tid & 63;
  const int wave = tid >> 6;
#pragma unroll
  for (int o = 0; o < NOBJ; ++o) {
    if (o >= n_obj) break;
    unsigned long long v = pk[o];
    for (int off = 32; off > 0; off >>= 1) {
      unsigned long long w = __shfl_down(v, off, 64);
      if (w > v) v = w;
    }
    if (lane == 0) s_part[wave][o] = v;
  }
  __syncthreads();
  if (tid < n_obj) {
    unsigned long long v = s_part[0][tid];
    const int nw = blockDim.x >> 6;
    for (int w = 1; w < nw; ++w) {
      const unsigned long long x = s_part[w][tid];
      if (x > v) v = x;
    }
    atomicMax(&prior_fo[(size_t)b * n_obj + tid], v);
  }
}

// Phase C: labels, CE, loc L1 for positives, conf_neg array.
__global__ __launch_bounds__(256) void mbl_loss_kernel(
    const float* __restrict__ locs, const float* __restrict__ scores,
    const float* __restrict__ boxes, const int* __restrict__ labels,
    const float* __restrict__ priors,
    const unsigned long long* __restrict__ prior_fo,
    const unsigned long long* __restrict__ best_pair,
    float* __restrict__ conf_neg, int* __restrict__ n_pos, double* __restrict__ sums,
    int P, int n_obj, int C) {
  const int b = blockIdx.y;
  const int p = blockIdx.x * blockDim.x + threadIdx.x;
  const int tid = threadIdx.x;
  __shared__ float s_box[MAX_OBJ][6];
  __shared__ int s_lab[MAX_OBJ];
  __shared__ unsigned s_fo[MAX_OBJ];
  for (int i = tid; i < n_obj * 6; i += blockDim.x)
    s_box[i / 6][i % 6] = boxes[(size_t)b * n_obj * 6 + i];
  for (int i = tid; i < n_obj; i += blockDim.x) {
    s_lab[i] = labels[(size_t)b * n_obj + i];
    s_fo[i] = 0xFFFFFFFFu - (unsigned)(prior_fo[(size_t)b * n_obj + i] & 0xFFFFFFFFull);
  }
  __syncthreads();

  int is_pos = 0;
  double confv = 0.0, locv = 0.0;
  if (p < P) {
    const unsigned long long bp = best_pair[(size_t)b * P + p];
    float best = __uint_as_float((unsigned)(bp >> 32));
    int obj = (int)(unsigned)(bp & 0xFFFFFFFFull);
    // forced matching: ascending o, last wins (numpy .at[].set semantics)
    for (int o = 0; o < n_obj; ++o)
      if (s_fo[o] == (unsigned)p) { obj = o; best = 1.0f; }
    const int lab = (best < 0.5f) ? 0 : s_lab[obj];

    const float* sp = scores + ((size_t)b * P + p) * C;
    float m = sp[0];
    for (int c = 1; c < C; ++c) m = fmaxf(m, sp[c]);
    float se = 0.f;
    for (int c = 0; c < C; ++c) se += expf(sp[c] - m);
    const float lse = m + logf(se);
    const float conf = (lab < 0) ? 0.f : (lse - sp[lab]);

    float cn = conf;
    if (lab > 0) {
      is_pos = 1;
      confv = (double)conf;
      const float* pr = priors + (size_t)p * 6;
      const float* pl = locs + ((size_t)b * P + p) * 6;
      float g[6];
      for (int i = 0; i < 3; ++i) {
        const float c0 = (s_box[obj][i] + s_box[obj][i + 3]) * 0.5f;
        const float sz = s_box[obj][i + 3] - s_box[obj][i];
        g[i] = (c0 - pr[i]) / (pr[i + 3] / 10.0f);
        g[i + 3] = logf(sz / pr[i + 3]) * 5.0f;
      }
      float ls = 0.f;
      for (int i = 0; i < 6; ++i) ls += fabsf(pl[i] - g[i]);
      locv = (double)ls;
      cn = 0.f;
    }
    conf_neg[(size_t)b * P + p] = cn;
  }

  __shared__ int r_np[256];
  __shared__ double r_c[256];
  __shared__ double r_l[256];
  r_np[tid] = is_pos;
  r_c[tid] = confv;
  r_l[tid] = locv;
  __syncthreads();
  for (int s = 128; s > 0; s >>= 1) {
    if (tid < s) {
      r_np[tid] += r_np[tid + s];
      r_c[tid] += r_c[tid + s];
      r_l[tid] += r_l[tid + s];
    }
    __syncthreads();
  }
  if (tid == 0 && r_np[0] > 0) {
    atomicAdd(&n_pos[b], r_np[0]);
    atomicAdd(&sums[0], r_c[0]);
    atomicAdd(&sums[1], r_l[0]);
  }
}

// Top-K machinery: exact MSB radix select on float bits (values >= 0).
__global__ void mbl_topk_init(const int* __restrict__ n_pos, int2* __restrict__ state,
                              unsigned* __restrict__ hist, int P, int ratio) {
  const int b = blockIdx.x;
  hist[(size_t)b * 256 + threadIdx.x] = 0u;
  if (threadIdx.x == 0) {
    long long K = (long long)ratio * (long long)n_pos[b];
    if (K > P) K = P;
    int2 st;
    st.x = 0;
    st.y = (int)K;
    state[b] = st;
  }
}

__global__ __launch_bounds__(256) void mbl_topk_hist(
    const float* __restrict__ conf_neg, const int2* __restrict__ state,
    unsigned* __restrict__ hist, int P, int shift) {
  const int b = blockIdx.y;
  __shared__ unsigned sh[256];
  sh[threadIdx.x] = 0u;
  __syncthreads();
  const unsigned prefix = (unsigned)state[b].x;
  const unsigned maskHigh = (shift == 24) ? 0u : (0xFFFFFFFFu << (shift + 8));
  const float* row = conf_neg + (size_t)b * P;
  const int chunk = (P + gridDim.x - 1) / gridDim.x;
  const int start = blockIdx.x * chunk;
  const int end = min(start + chunk, P);
  for (int p = start + threadIdx.x; p < end; p += blockDim.x) {
    const unsigned u = __float_as_uint(row[p]);
    if ((u & maskHigh) == (prefix & maskHigh))
      atomicAdd(&sh[(u >> shift) & 255u], 1u);
  }
  __syncthreads();
  if (sh[threadIdx.x]) atomicAdd(&hist[(size_t)b * 256 + threadIdx.x], sh[threadIdx.x]);
}

__global__ __launch_bounds__(256) void mbl_topk_select(
    unsigned* __restrict__ hist, int2* __restrict__ state, int shift) {
  const int b = blockIdx.x;
  unsigned* h = hist + (size_t)b * 256;
  __shared__ unsigned sh[256];
  sh[threadIdx.x] = h[threadIdx.x];
  __syncthreads();
  if (threadIdx.x == 0) {
    int2 st = state[b];
    const unsigned prefix = (unsigned)st.x;
    const int remk = st.y;
    int acc = 0, sel = 0;
    for (int bin = 255; bin >= 0; --bin) {
      const int c = (int)sh[bin];
      if (acc + c >= remk) { sel = bin; break; }
      acc += c;
    }
    st.x = (int)(prefix | ((unsigned)sel << shift));
    st.y = remk - acc;
    state[b] = st;
  }
  h[threadIdx.x] = 0u;  // ready for next round
}

__global__ __launch_bounds__(256) void mbl_topk_sum(
    const float* __restrict__ conf_neg, const int2* __restrict__ state,
    double* __restrict__ sums, int P) {
  const int b = blockIdx.y;
  const unsigned prefix = (unsigned)state[b].x;
  const float* row = conf_neg + (size_t)b * P;
  const int chunk = (P + gridDim.x - 1) / gridDim.x;
  const int start = blockIdx.x * chunk;
  const int end = min(start + chunk, P);
  double local = 0.0;
  for (int p = start + threadIdx.x; p < end; p += blockDim.x) {
    const float v = row[p];
    if (__float_as_uint(v) > prefix) local += (double)v;
  }
  __shared__ double red[256];
  red[threadIdx.x] = local;
  __syncthreads();
  for (int s = 128; s > 0; s >>= 1) {
    if (threadIdx.x < s) red[threadIdx.x] += red[threadIdx.x + s];
    __syncthreads();
  }
  if (threadIdx.x == 0 && red[0] != 0.0) atomicAdd(&sums[2], red[0]);
}

__global__ void mbl_finalize(const double* __restrict__ sums, const int* __restrict__ n_pos,
                             const int2* __restrict__ state, int B, float* __restrict__ out) {
  if (threadIdx.x == 0 && blockIdx.x == 0) {
    double tp = 0.0;
    double hard = sums[2];
    for (int b = 0; b < B; ++b) {
      tp += (double)n_pos[b];
      // remK copies of the tie value t
      hard += (double)state[b].y * (double)__uint_as_float((unsigned)state[b].x);
    }
    out[0] = (float)((hard + sums[0]) / tp);
    out[1] = (float)(sums[1] / (tp * 6.0));
  }
}

extern "C" void kernel_launch(void* const* d_in, const int* in_sizes, int n_in,
                              void* d_out, int out_size, void* d_ws, size_t ws_size,
                              hipStream_t stream) {
  const float* locs = (const float*)d_in[0];
  const float* scores = (const float*)d_in[1];
  const float* boxes = (const float*)d_in[2];
  const int* labels = (const int*)d_in[3];
  const float* priors = (const float*)d_in[4];

  const long long sz_locs = (long long)in_sizes[0];
  const long long sz_scores = (long long)in_sizes[1];
  const long long sz_priors = (long long)in_sizes[4];
  const int P = (int)(sz_priors / 6);
  const int B = (int)(sz_locs / sz_priors);
  const int n_obj = in_sizes[3] / B;
  const int C = (int)(sz_scores * 6 / sz_locs);

  char* ws = (char*)d_ws;
  size_t off = 0;
  double* sums = (double*)(ws + off);
  off += 32;  // 3 doubles + pad
  int2* state = (int2*)(ws + off);
  off += (size_t)B * sizeof(int2);
  int* n_pos = (int*)(ws + off);
  off += ((size_t)B * 4 + 7) & ~(size_t)7;
  unsigned long long* prior_fo = (unsigned long long*)(ws + off);
  off += (size_t)B * n_obj * 8;
  unsigned* hist = (unsigned*)(ws + off);
  off += (size_t)B * 256 * 4;
  float* conf_neg = (float*)(ws + off);
  off += ((size_t)B * P * 4 + 7) & ~(size_t)7;
  unsigned long long* best_pair = (unsigned long long*)(ws + off);
  off += (size_t)B * P * 8;
  (void)ws_size;  // requires ~25 MB; assumed available

  int initN = B * n_obj;
  if (initN < B) initN = B;
  if (initN < 3) initN = 3;
  mbl_init_ws<<<(initN + 255) / 256, 256, 0, stream>>>(sums, n_pos, prior_fo, B, n_obj);

  const dim3 mgrid((P + 256 * PF_ITEMS - 1) / (256 * PF_ITEMS), B);
  if (n_obj <= 16) {
    mbl_match_kernel<16><<<mgrid, 256, 0, stream>>>(boxes, priors, prior_fo, best_pair, P, n_obj);
  } else if (n_obj <= 32) {
    mbl_match_kernel<32><<<mgrid, 256, 0, stream>>>(boxes, priors, prior_fo, best_pair, P, n_obj);
  } else {
    mbl_match_kernel<64><<<mgrid, 256, 0, stream>>>(boxes, priors, prior_fo, best_pair, P, n_obj);
  }

  const dim3 lgrid((P + 255) / 256, B);
  mbl_loss_kernel<<<lgrid, 256, 0, stream>>>(locs, scores, boxes, labels, priors, prior_fo,
                                             best_pair, conf_neg, n_pos, sums, P, n_obj, C);

  mbl_topk_init<<<B, 256, 0, stream>>>(n_pos, state, hist, P, 3);
  const dim3 tgrid(TOPK_CHUNKS, B);
  for (int shift = 24; shift >= 0; shift -= 8) {
    mbl_topk_hist<<<tgrid, 256, 0, stream>>>(conf_neg, state, hist, P, shift);
    mbl_topk_select<<<B, 256, 0, stream>>>(hist, state, shift);
  }
  mbl_topk_sum<<<tgrid, 256, 0, stream>>>(conf_neg, state, sums, P);
  mbl_finalize<<<1, 64, 0, stream>>>(sums, n_pos, state, B, (float*)d_out);
}